// Round 6
// baseline (106.207 us; speedup 1.0000x reference)
//
#include <hip/hip_runtime.h>
#include <math.h>

// Chamfer loss, B=4, C=3, Np=Ng=8192, fp32.
// Round 10: corrected cycle model — v_pk_fma_f32 occupies the 32-lane fp32
// datapath for 4 cyc/wave64 (packed halves issue slots, NOT datapath time).
// 2-pass algorithm floor = 2.15e9 lane-ops / 7.86e13 = 27.3us; R5's VALU
// busy-time (28.9us) is already 106% of that => sweep is datapath-bound.
// This round closes the dur-vs-busy gap (44.4 vs 28.9): drop the manual
// depth-2 pipeline (2-iteration scheduling window) and FULLY UNROLL the
// NJJ=64 loop with float4 (ds_read_b128 + imm offsets) tile reads — the
// compiler hoists loads across the whole body with its own lgkmcnt
// watermarks. DS insts halve (2 b128 vs 4 b64/jj); rotation movs gone.
// Structure unchanged: YSPL=64 -> 2048 wgs (exactly 8 wg/CU), plain-store
// publish, stream-ordered reduce. ws gates as before; R0 fused fallback.

#define B_       4
#define N_       8192
#define THREADS  256
#define RX       8
#define XB       (THREADS * RX)        // 2048 x-points per workgroup
#define XBLKS    (N_ / XB)             // 4
#define NPB      (2 * B_)              // 8 (pass,b) slabs
#define RTHREADS 128

typedef float v2f __attribute__((ext_vector_type(2)));

__device__ __forceinline__ v2f pk_fma(v2f a, v2f b, v2f c) {
    v2f d;
    asm("v_pk_fma_f32 %0, %1, %2, %3" : "=v"(d) : "v"(a), "v"(b), "v"(c));
    return d;
}

__device__ __forceinline__ float min3f(float a, float b, float c) {
    float d;
    asm("v_min3_f32 %0, %1, %2, %3" : "=v"(d) : "v"(a), "v"(b), "v"(c));
    return d;
}

// ---------------- primary path: sweep + reduce, atomic-free ----------------
// partial layout: [pb][ysplit][x:8192] floats.

template<int YSPL>
__global__ __launch_bounds__(THREADS)
void chamfer_sweep_t(const float* __restrict__ P, const float* __restrict__ G,
                     float* __restrict__ partial)
{
    constexpr int YCHUNK = N_ / YSPL;
    constexpr int NJJ    = YCHUNK / 2;
    // Pair-records: slot 2*jj = (gx0,gx1,gy0,gy1), 2*jj+1 = (gz0,gz1,g2_0,g2_1)
    __shared__ float4 ytile[2 * NJJ];

    const int t      = threadIdx.x;
    const int xblk   = blockIdx.x;     // 0..XBLKS-1
    const int ysplit = blockIdx.y;     // 0..YSPL-1
    const int bz     = blockIdx.z;     // 0..7
    const int pass   = bz >> 2;        // 0: X=predict, 1: X=gt
    const int b      = bz & 3;

    const float* Xb = (pass ? G : P) + (size_t)b * 3 * N_;
    const float* Yb = (pass ? P : G) + (size_t)b * 3 * N_;

    // Stage y-pair records.
    const int ybase = ysplit * YCHUNK;
    if (t < NJJ) {
        const int n0 = ybase + 2 * t;
        float2 x01 = *(const float2*)&Yb[n0];
        float2 y01 = *(const float2*)&Yb[N_ + n0];
        float2 z01 = *(const float2*)&Yb[2 * N_ + n0];
        float w0 = fmaf(x01.x, x01.x, fmaf(y01.x, y01.x, z01.x * z01.x));
        float w1 = fmaf(x01.y, x01.y, fmaf(y01.y, y01.y, z01.y * z01.y));
        ytile[2 * t]     = make_float4(x01.x, x01.y, y01.x, y01.y);
        ytile[2 * t + 1] = make_float4(z01.x, z01.y, w0, w1);
    }

    // RX x-points per thread; -2*coord duplicated into both halves.
    const int xbase = xblk * XB;
    v2f m2x2[RX], m2y2[RX], m2z2[RX];
    float mn[RX];
#pragma unroll
    for (int r = 0; r < RX; ++r) {
        const int n = xbase + r * THREADS + t;
        float px = Xb[n];
        float py = Xb[N_ + n];
        float pz = Xb[2 * N_ + n];
        float ax = -2.0f * px, ay = -2.0f * py, az = -2.0f * pz;
        m2x2[r] = (v2f){ax, ax};
        m2y2[r] = (v2f){ay, ay};
        m2z2[r] = (v2f){az, az};
        mn[r]   = 3.4e38f;
    }
    __syncthreads();

    // Fully-unrolled sweep: one scheduling region; compiler hoists the
    // 2*NJJ ds_read_b128 (imm offsets off one base) ahead of consumers
    // with fine-grained lgkmcnt watermarks.
#pragma unroll
    for (int jj = 0; jj < NJJ; ++jj) {
        float4 a4 = ytile[2 * jj];       // (gx0,gx1,gy0,gy1)
        float4 b4 = ytile[2 * jj + 1];   // (gz0,gz1,g2_0,g2_1)
        v2f gx2 = (v2f){a4.x, a4.y};
        v2f gy2 = (v2f){a4.z, a4.w};
        v2f gz2 = (v2f){b4.x, b4.y};
        v2f gw2 = (v2f){b4.z, b4.w};
#pragma unroll
        for (int r = 0; r < RX; ++r) {
            v2f s = pk_fma(m2z2[r], gz2, gw2);
            s = pk_fma(m2y2[r], gy2, s);
            s = pk_fma(m2x2[r], gx2, s);
            mn[r] = min3f(mn[r], s.x, s.y);
        }
    }

    // Epilogue: p2 recomputed from the -2p registers (p = -a/2 => p2 = sumsq/4).
    float* pout = partial + ((size_t)bz * YSPL + ysplit) * N_ + xbase;
#pragma unroll
    for (int r = 0; r < RX; ++r) {
        float ax = m2x2[r].x, ay = m2y2[r].x, az = m2z2[r].x;
        float p2 = 0.25f * fmaf(ax, ax, fmaf(ay, ay, az * az));
        pout[r * THREADS + t] = fmaxf(mn[r] + p2, 1e-12f);
    }
}

// K2: per 4 x-slots: min over YSPL partials (float4), sqrt, block tree-sum.
template<int YSPL>
__global__ __launch_bounds__(RTHREADS)
void chamfer_reduce1_t(const float* __restrict__ partial,
                       float* __restrict__ gsum2)
{
    __shared__ float red[RTHREADS];
    const int g  = blockIdx.x * RTHREADS + threadIdx.x;  // [0, 16384)
    const int pb = g >> 11;                              // 0..7
    const int xq = g & 2047;                             // float4 index
    const float4* p = (const float4*)(partial + (size_t)pb * YSPL * N_) + xq;
    float4 m = p[0];
#pragma unroll
    for (int ys = 1; ys < YSPL; ++ys) {
        float4 v = p[(size_t)ys * (N_ / 4)];
        m.x = fminf(m.x, v.x); m.y = fminf(m.y, v.y);
        m.z = fminf(m.z, v.z); m.w = fminf(m.w, v.w);
    }
    red[threadIdx.x] = sqrtf(m.x) + sqrtf(m.y) + sqrtf(m.z) + sqrtf(m.w);
    __syncthreads();
    for (int off = RTHREADS / 2; off > 0; off >>= 1) {
        if (threadIdx.x < off) red[threadIdx.x] += red[threadIdx.x + off];
        __syncthreads();
    }
    if (threadIdx.x == 0) gsum2[blockIdx.x] = red[0];
}

// K3: deterministic final sum of 128 block sums.
__global__ __launch_bounds__(RTHREADS)
void chamfer_final_kernel(const float* __restrict__ gsum2, float* __restrict__ out)
{
    __shared__ float red[RTHREADS];
    red[threadIdx.x] = gsum2[threadIdx.x];
    __syncthreads();
    for (int off = RTHREADS / 2; off > 0; off >>= 1) {
        if (threadIdx.x < off) red[threadIdx.x] += red[threadIdx.x + off];
        __syncthreads();
    }
    if (threadIdx.x == 0) out[0] = red[0] * (1.0f / 65536.0f);   // denom = B*(Ng+Np)
}

// ---------------- fallback path (known-good R0, 257KB ws) ----------------
#define LRX      8
#define LXB      (THREADS * LRX)       // 2048
#define LXBLKS   (N_ / LXB)            // 4
#define LYSPL    32
#define LYCHUNK  (N_ / LYSPL)          // 256
#define LNGROUPS (2 * B_ * LXBLKS)     // 32
#define POISON   0xAAAAAAAAu

__global__ __launch_bounds__(THREADS)
void chamfer_fused_kernel(const float* __restrict__ P, const float* __restrict__ G,
                          unsigned* __restrict__ mins, unsigned* __restrict__ gcnt,
                          unsigned* __restrict__ fcnt, float* __restrict__ gsum,
                          float* __restrict__ out)
{
    __shared__ float4 ytile[2 * (LYCHUNK / 2)];
    __shared__ float red[THREADS];
    __shared__ unsigned s_ticket;

    const int t      = threadIdx.x;
    const int xblk   = blockIdx.x;
    const int ysplit = blockIdx.y;
    const int bz     = blockIdx.z;
    const int pass   = bz >> 2;
    const int b      = bz & 3;
    const int gid    = bz * LXBLKS + xblk;

    const float* Xb = (pass ? G : P) + (size_t)b * 3 * N_;
    const float* Yb = (pass ? P : G) + (size_t)b * 3 * N_;

    const int ybase = ysplit * LYCHUNK;
    if (t < LYCHUNK / 2) {
        const int n0 = ybase + 2 * t;
        float2 x01 = *(const float2*)&Yb[n0];
        float2 y01 = *(const float2*)&Yb[N_ + n0];
        float2 z01 = *(const float2*)&Yb[2 * N_ + n0];
        float w0 = fmaf(x01.x, x01.x, fmaf(y01.x, y01.x, z01.x * z01.x));
        float w1 = fmaf(x01.y, x01.y, fmaf(y01.y, y01.y, z01.y * z01.y));
        ytile[2 * t]     = make_float4(x01.x, x01.y, y01.x, y01.y);
        ytile[2 * t + 1] = make_float4(z01.x, z01.y, w0, w1);
    }

    const int xbase = xblk * LXB;
    v2f m2x2[LRX], m2y2[LRX], m2z2[LRX];
    float p2[LRX], mn[LRX];
#pragma unroll
    for (int r = 0; r < LRX; ++r) {
        const int n = xbase + r * THREADS + t;
        float px = Xb[n];
        float py = Xb[N_ + n];
        float pz = Xb[2 * N_ + n];
        p2[r]   = fmaf(px, px, fmaf(py, py, pz * pz));
        float ax = -2.0f * px, ay = -2.0f * py, az = -2.0f * pz;
        m2x2[r] = (v2f){ax, ax};
        m2y2[r] = (v2f){ay, ay};
        m2z2[r] = (v2f){az, az};
        mn[r]   = 3.4e38f;
    }
    __syncthreads();

#pragma unroll 2
    for (int jj = 0; jj < LYCHUNK / 2; ++jj) {
        float4 a4 = ytile[2 * jj];
        float4 b4 = ytile[2 * jj + 1];
        v2f gx2 = (v2f){a4.x, a4.y};
        v2f gy2 = (v2f){a4.z, a4.w};
        v2f gz2 = (v2f){b4.x, b4.y};
        v2f gw2 = (v2f){b4.z, b4.w};
#pragma unroll
        for (int r = 0; r < LRX; ++r) {
            v2f s = pk_fma(m2z2[r], gz2, gw2);
            s = pk_fma(m2y2[r], gy2, s);
            s = pk_fma(m2x2[r], gx2, s);
            mn[r] = fminf(fminf(mn[r], s.x), s.y);
        }
    }

    unsigned* mybase = mins + (size_t)(pass * B_ + b) * N_ + xbase;
#pragma unroll
    for (int r = 0; r < LRX; ++r) {
        float v = fmaxf(mn[r] + p2[r], 1e-12f);
        atomicMin(&mybase[r * THREADS + t], __float_as_uint(v));
    }

    __syncthreads();
    if (t == 0) {
        __threadfence();
        s_ticket = atomicAdd(&gcnt[gid], 1u);
    }
    __syncthreads();
    if (s_ticket != POISON + (unsigned)(LYSPL - 1)) return;

    __threadfence();
    const uint4* vmin = (const uint4*)(mins + (size_t)(pass * B_ + b) * N_ + xbase);
    uint4 q0 = vmin[t];
    uint4 q1 = vmin[THREADS + t];
    float a = sqrtf(__uint_as_float(q0.x)) + sqrtf(__uint_as_float(q0.y))
            + sqrtf(__uint_as_float(q0.z)) + sqrtf(__uint_as_float(q0.w))
            + sqrtf(__uint_as_float(q1.x)) + sqrtf(__uint_as_float(q1.y))
            + sqrtf(__uint_as_float(q1.z)) + sqrtf(__uint_as_float(q1.w));
    red[t] = a;
    __syncthreads();
    for (int off = 128; off > 0; off >>= 1) {
        if (t < off) red[t] += red[t + off];
        __syncthreads();
    }
    if (t == 0) {
        gsum[gid] = red[0];
        __threadfence();
        s_ticket = atomicAdd(fcnt, 1u);
    }
    __syncthreads();
    if (s_ticket != POISON + (unsigned)(LNGROUPS - 1)) return;

    __threadfence();
    red[t] = (t < LNGROUPS) ? gsum[t] : 0.0f;
    __syncthreads();
    for (int off = 128; off > 0; off >>= 1) {
        if (t < off) red[t] += red[t + off];
        __syncthreads();
    }
    if (t == 0) out[0] = red[0] * (1.0f / 65536.0f);
}

extern "C" void kernel_launch(void* const* d_in, const int* in_sizes, int n_in,
                              void* d_out, int out_size, void* d_ws, size_t ws_size,
                              hipStream_t stream)
{
    const float* P = (const float*)d_in[0];   // predict_pc [4,3,8192]
    const float* G = (const float*)d_in[1];   // gt_pc      [4,3,8192]
    float* out = (float*)d_out;               // scalar

    const size_t need64 = ((size_t)NPB * 64 * N_ + 256) * 4;   // ~16.8 MB
    const size_t need32 = ((size_t)NPB * 32 * N_ + 256) * 4;   // ~8.4 MB

    if (ws_size >= need64) {
        float* partial = (float*)d_ws;
        float* gsum2   = partial + (size_t)NPB * 64 * N_;
        chamfer_sweep_t<64><<<dim3(XBLKS, 64, NPB), THREADS, 0, stream>>>(P, G, partial);
        chamfer_reduce1_t<64><<<dim3(128), RTHREADS, 0, stream>>>(partial, gsum2);
        chamfer_final_kernel<<<dim3(1), RTHREADS, 0, stream>>>(gsum2, out);
    } else if (ws_size >= need32) {
        float* partial = (float*)d_ws;
        float* gsum2   = partial + (size_t)NPB * 32 * N_;
        chamfer_sweep_t<32><<<dim3(XBLKS, 32, NPB), THREADS, 0, stream>>>(P, G, partial);
        chamfer_reduce1_t<32><<<dim3(128), RTHREADS, 0, stream>>>(partial, gsum2);
        chamfer_final_kernel<<<dim3(1), RTHREADS, 0, stream>>>(gsum2, out);
    } else {
        unsigned* w    = (unsigned*)d_ws;
        unsigned* mins = w;                   // 65536 words
        unsigned* gcnt = w + 65536;           // 32 words
        unsigned* fcnt = w + 65600;           // 1 word
        float*    gsum = (float*)(w + 65664); // 32 words
        dim3 grid(LXBLKS, LYSPL, NPB);
        chamfer_fused_kernel<<<grid, THREADS, 0, stream>>>(P, G, mins, gcnt, fcnt, gsum, out);
    }
}

// Round 7
// 106.055 us; speedup vs baseline: 1.0014x; 1.0014x over previous
//
#include <hip/hip_runtime.h>
#include <math.h>

// Chamfer loss, B=4, C=3, Np=Ng=8192, fp32.
// Round 11: LDS-pipe theory. R4/R5/R6 (manual pipe / rotated / full-unroll)
// all pin at 44-46us, VALU busy-time ~28.5us, VALUBusy ~62% — a shared-pipe
// serializer, not scheduling. Model: per-CU LDS unit services 2 ds_read_b128
// per wave-jj (~24cyc each incl. broadcast); at 32 waves/CU that's ~1536cyc
// of LDS service per 896cyc of SIMD datapath => LDS-bound, VALU duty 58%
// (matches 62% measured, predicts ~45us). Fix: RX 8->16 — same 2 b128 now
// feed 224 datapath cyc (48 pk_fma + 16 min3) => LDS demand < datapath
// period => VALU-bound. Prediction: busy-time invariant ~27-29us, dur
// 31-37us, VALUBusy 75-90%. XBLKS=2, grid (2,64,8)=1024 wgs. unroll 8
// (R3 lesson: no launch-bounds clamp; let regs land where they land).

#define B_       4
#define N_       8192
#define THREADS  256
#define RX       16
#define XB       (THREADS * RX)        // 4096 x-points per workgroup
#define XBLKS    (N_ / XB)             // 2
#define NPB      (2 * B_)              // 8 (pass,b) slabs
#define RTHREADS 128

typedef float v2f __attribute__((ext_vector_type(2)));

__device__ __forceinline__ v2f pk_fma(v2f a, v2f b, v2f c) {
    v2f d;
    asm("v_pk_fma_f32 %0, %1, %2, %3" : "=v"(d) : "v"(a), "v"(b), "v"(c));
    return d;
}

__device__ __forceinline__ float min3f(float a, float b, float c) {
    float d;
    asm("v_min3_f32 %0, %1, %2, %3" : "=v"(d) : "v"(a), "v"(b), "v"(c));
    return d;
}

// ---------------- primary path: sweep + reduce, atomic-free ----------------
// partial layout: [pb][ysplit][x:8192] floats.

template<int YSPL>
__global__ __launch_bounds__(THREADS)
void chamfer_sweep_t(const float* __restrict__ P, const float* __restrict__ G,
                     float* __restrict__ partial)
{
    constexpr int YCHUNK = N_ / YSPL;
    constexpr int NJJ    = YCHUNK / 2;
    // Pair-records: slot 2*jj = (gx0,gx1,gy0,gy1), 2*jj+1 = (gz0,gz1,g2_0,g2_1)
    __shared__ float4 ytile[2 * NJJ];

    const int t      = threadIdx.x;
    const int xblk   = blockIdx.x;     // 0..XBLKS-1
    const int ysplit = blockIdx.y;     // 0..YSPL-1
    const int bz     = blockIdx.z;     // 0..7
    const int pass   = bz >> 2;        // 0: X=predict, 1: X=gt
    const int b      = bz & 3;

    const float* Xb = (pass ? G : P) + (size_t)b * 3 * N_;
    const float* Yb = (pass ? P : G) + (size_t)b * 3 * N_;

    // Stage y-pair records.
    const int ybase = ysplit * YCHUNK;
    if (t < NJJ) {
        const int n0 = ybase + 2 * t;
        float2 x01 = *(const float2*)&Yb[n0];
        float2 y01 = *(const float2*)&Yb[N_ + n0];
        float2 z01 = *(const float2*)&Yb[2 * N_ + n0];
        float w0 = fmaf(x01.x, x01.x, fmaf(y01.x, y01.x, z01.x * z01.x));
        float w1 = fmaf(x01.y, x01.y, fmaf(y01.y, y01.y, z01.y * z01.y));
        ytile[2 * t]     = make_float4(x01.x, x01.y, y01.x, y01.y);
        ytile[2 * t + 1] = make_float4(z01.x, z01.y, w0, w1);
    }

    // RX x-points per thread; -2*coord duplicated into both halves.
    const int xbase = xblk * XB;
    v2f m2x2[RX], m2y2[RX], m2z2[RX];
    float mn[RX];
#pragma unroll
    for (int r = 0; r < RX; ++r) {
        const int n = xbase + r * THREADS + t;
        float px = Xb[n];
        float py = Xb[N_ + n];
        float pz = Xb[2 * N_ + n];
        float ax = -2.0f * px, ay = -2.0f * py, az = -2.0f * pz;
        m2x2[r] = (v2f){ax, ax};
        m2y2[r] = (v2f){ay, ay};
        m2z2[r] = (v2f){az, az};
        mn[r]   = 3.4e38f;
    }
    __syncthreads();

    // Sweep: 2 ds_read_b128 per jj feed 48 pk_fma + 16 min3 (224 datapath cyc)
    // => LDS pipe demand per CU is under the datapath period.
#pragma unroll 8
    for (int jj = 0; jj < NJJ; ++jj) {
        float4 a4 = ytile[2 * jj];       // (gx0,gx1,gy0,gy1)
        float4 b4 = ytile[2 * jj + 1];   // (gz0,gz1,g2_0,g2_1)
        v2f gx2 = (v2f){a4.x, a4.y};
        v2f gy2 = (v2f){a4.z, a4.w};
        v2f gz2 = (v2f){b4.x, b4.y};
        v2f gw2 = (v2f){b4.z, b4.w};
#pragma unroll
        for (int r = 0; r < RX; ++r) {
            v2f s = pk_fma(m2z2[r], gz2, gw2);
            s = pk_fma(m2y2[r], gy2, s);
            s = pk_fma(m2x2[r], gx2, s);
            mn[r] = min3f(mn[r], s.x, s.y);
        }
    }

    // Epilogue: p2 recomputed from the -2p registers (p = -a/2 => p2 = sumsq/4).
    float* pout = partial + ((size_t)bz * YSPL + ysplit) * N_ + xbase;
#pragma unroll
    for (int r = 0; r < RX; ++r) {
        float ax = m2x2[r].x, ay = m2y2[r].x, az = m2z2[r].x;
        float p2 = 0.25f * fmaf(ax, ax, fmaf(ay, ay, az * az));
        pout[r * THREADS + t] = fmaxf(mn[r] + p2, 1e-12f);
    }
}

// K2: per 4 x-slots: min over YSPL partials (float4), sqrt, block tree-sum.
template<int YSPL>
__global__ __launch_bounds__(RTHREADS)
void chamfer_reduce1_t(const float* __restrict__ partial,
                       float* __restrict__ gsum2)
{
    __shared__ float red[RTHREADS];
    const int g  = blockIdx.x * RTHREADS + threadIdx.x;  // [0, 16384)
    const int pb = g >> 11;                              // 0..7
    const int xq = g & 2047;                             // float4 index
    const float4* p = (const float4*)(partial + (size_t)pb * YSPL * N_) + xq;
    float4 m = p[0];
#pragma unroll
    for (int ys = 1; ys < YSPL; ++ys) {
        float4 v = p[(size_t)ys * (N_ / 4)];
        m.x = fminf(m.x, v.x); m.y = fminf(m.y, v.y);
        m.z = fminf(m.z, v.z); m.w = fminf(m.w, v.w);
    }
    red[threadIdx.x] = sqrtf(m.x) + sqrtf(m.y) + sqrtf(m.z) + sqrtf(m.w);
    __syncthreads();
    for (int off = RTHREADS / 2; off > 0; off >>= 1) {
        if (threadIdx.x < off) red[threadIdx.x] += red[threadIdx.x + off];
        __syncthreads();
    }
    if (threadIdx.x == 0) gsum2[blockIdx.x] = red[0];
}

// K3: deterministic final sum of 128 block sums.
__global__ __launch_bounds__(RTHREADS)
void chamfer_final_kernel(const float* __restrict__ gsum2, float* __restrict__ out)
{
    __shared__ float red[RTHREADS];
    red[threadIdx.x] = gsum2[threadIdx.x];
    __syncthreads();
    for (int off = RTHREADS / 2; off > 0; off >>= 1) {
        if (threadIdx.x < off) red[threadIdx.x] += red[threadIdx.x + off];
        __syncthreads();
    }
    if (threadIdx.x == 0) out[0] = red[0] * (1.0f / 65536.0f);   // denom = B*(Ng+Np)
}

// ---------------- fallback path (known-good R0, 257KB ws) ----------------
#define LRX      8
#define LXB      (THREADS * LRX)       // 2048
#define LXBLKS   (N_ / LXB)            // 4
#define LYSPL    32
#define LYCHUNK  (N_ / LYSPL)          // 256
#define LNGROUPS (2 * B_ * LXBLKS)     // 32
#define POISON   0xAAAAAAAAu

__global__ __launch_bounds__(THREADS)
void chamfer_fused_kernel(const float* __restrict__ P, const float* __restrict__ G,
                          unsigned* __restrict__ mins, unsigned* __restrict__ gcnt,
                          unsigned* __restrict__ fcnt, float* __restrict__ gsum,
                          float* __restrict__ out)
{
    __shared__ float4 ytile[2 * (LYCHUNK / 2)];
    __shared__ float red[THREADS];
    __shared__ unsigned s_ticket;

    const int t      = threadIdx.x;
    const int xblk   = blockIdx.x;
    const int ysplit = blockIdx.y;
    const int bz     = blockIdx.z;
    const int pass   = bz >> 2;
    const int b      = bz & 3;
    const int gid    = bz * LXBLKS + xblk;

    const float* Xb = (pass ? G : P) + (size_t)b * 3 * N_;
    const float* Yb = (pass ? P : G) + (size_t)b * 3 * N_;

    const int ybase = ysplit * LYCHUNK;
    if (t < LYCHUNK / 2) {
        const int n0 = ybase + 2 * t;
        float2 x01 = *(const float2*)&Yb[n0];
        float2 y01 = *(const float2*)&Yb[N_ + n0];
        float2 z01 = *(const float2*)&Yb[2 * N_ + n0];
        float w0 = fmaf(x01.x, x01.x, fmaf(y01.x, y01.x, z01.x * z01.x));
        float w1 = fmaf(x01.y, x01.y, fmaf(y01.y, y01.y, z01.y * z01.y));
        ytile[2 * t]     = make_float4(x01.x, x01.y, y01.x, y01.y);
        ytile[2 * t + 1] = make_float4(z01.x, z01.y, w0, w1);
    }

    const int xbase = xblk * LXB;
    v2f m2x2[LRX], m2y2[LRX], m2z2[LRX];
    float p2[LRX], mn[LRX];
#pragma unroll
    for (int r = 0; r < LRX; ++r) {
        const int n = xbase + r * THREADS + t;
        float px = Xb[n];
        float py = Xb[N_ + n];
        float pz = Xb[2 * N_ + n];
        p2[r]   = fmaf(px, px, fmaf(py, py, pz * pz));
        float ax = -2.0f * px, ay = -2.0f * py, az = -2.0f * pz;
        m2x2[r] = (v2f){ax, ax};
        m2y2[r] = (v2f){ay, ay};
        m2z2[r] = (v2f){az, az};
        mn[r]   = 3.4e38f;
    }
    __syncthreads();

#pragma unroll 2
    for (int jj = 0; jj < LYCHUNK / 2; ++jj) {
        float4 a4 = ytile[2 * jj];
        float4 b4 = ytile[2 * jj + 1];
        v2f gx2 = (v2f){a4.x, a4.y};
        v2f gy2 = (v2f){a4.z, a4.w};
        v2f gz2 = (v2f){b4.x, b4.y};
        v2f gw2 = (v2f){b4.z, b4.w};
#pragma unroll
        for (int r = 0; r < LRX; ++r) {
            v2f s = pk_fma(m2z2[r], gz2, gw2);
            s = pk_fma(m2y2[r], gy2, s);
            s = pk_fma(m2x2[r], gx2, s);
            mn[r] = fminf(fminf(mn[r], s.x), s.y);
        }
    }

    unsigned* mybase = mins + (size_t)(pass * B_ + b) * N_ + xbase;
#pragma unroll
    for (int r = 0; r < LRX; ++r) {
        float v = fmaxf(mn[r] + p2[r], 1e-12f);
        atomicMin(&mybase[r * THREADS + t], __float_as_uint(v));
    }

    __syncthreads();
    if (t == 0) {
        __threadfence();
        s_ticket = atomicAdd(&gcnt[gid], 1u);
    }
    __syncthreads();
    if (s_ticket != POISON + (unsigned)(LYSPL - 1)) return;

    __threadfence();
    const uint4* vmin = (const uint4*)(mins + (size_t)(pass * B_ + b) * N_ + xbase);
    uint4 q0 = vmin[t];
    uint4 q1 = vmin[THREADS + t];
    float a = sqrtf(__uint_as_float(q0.x)) + sqrtf(__uint_as_float(q0.y))
            + sqrtf(__uint_as_float(q0.z)) + sqrtf(__uint_as_float(q0.w))
            + sqrtf(__uint_as_float(q1.x)) + sqrtf(__uint_as_float(q1.y))
            + sqrtf(__uint_as_float(q1.z)) + sqrtf(__uint_as_float(q1.w));
    red[t] = a;
    __syncthreads();
    for (int off = 128; off > 0; off >>= 1) {
        if (t < off) red[t] += red[t + off];
        __syncthreads();
    }
    if (t == 0) {
        gsum[gid] = red[0];
        __threadfence();
        s_ticket = atomicAdd(fcnt, 1u);
    }
    __syncthreads();
    if (s_ticket != POISON + (unsigned)(LNGROUPS - 1)) return;

    __threadfence();
    red[t] = (t < LNGROUPS) ? gsum[t] : 0.0f;
    __syncthreads();
    for (int off = 128; off > 0; off >>= 1) {
        if (t < off) red[t] += red[t + off];
        __syncthreads();
    }
    if (t == 0) out[0] = red[0] * (1.0f / 65536.0f);
}

extern "C" void kernel_launch(void* const* d_in, const int* in_sizes, int n_in,
                              void* d_out, int out_size, void* d_ws, size_t ws_size,
                              hipStream_t stream)
{
    const float* P = (const float*)d_in[0];   // predict_pc [4,3,8192]
    const float* G = (const float*)d_in[1];   // gt_pc      [4,3,8192]
    float* out = (float*)d_out;               // scalar

    const size_t need64 = ((size_t)NPB * 64 * N_ + 256) * 4;   // ~16.8 MB
    const size_t need32 = ((size_t)NPB * 32 * N_ + 256) * 4;   // ~8.4 MB

    if (ws_size >= need64) {
        float* partial = (float*)d_ws;
        float* gsum2   = partial + (size_t)NPB * 64 * N_;
        chamfer_sweep_t<64><<<dim3(XBLKS, 64, NPB), THREADS, 0, stream>>>(P, G, partial);
        chamfer_reduce1_t<64><<<dim3(128), RTHREADS, 0, stream>>>(partial, gsum2);
        chamfer_final_kernel<<<dim3(1), RTHREADS, 0, stream>>>(gsum2, out);
    } else if (ws_size >= need32) {
        float* partial = (float*)d_ws;
        float* gsum2   = partial + (size_t)NPB * 32 * N_;
        chamfer_sweep_t<32><<<dim3(XBLKS, 32, NPB), THREADS, 0, stream>>>(P, G, partial);
        chamfer_reduce1_t<32><<<dim3(128), RTHREADS, 0, stream>>>(partial, gsum2);
        chamfer_final_kernel<<<dim3(1), RTHREADS, 0, stream>>>(gsum2, out);
    } else {
        unsigned* w    = (unsigned*)d_ws;
        unsigned* mins = w;                   // 65536 words
        unsigned* gcnt = w + 65536;           // 32 words
        unsigned* fcnt = w + 65600;           // 1 word
        float*    gsum = (float*)(w + 65664); // 32 words
        dim3 grid(LXBLKS, LYSPL, NPB);
        chamfer_fused_kernel<<<grid, THREADS, 0, stream>>>(P, G, mins, gcnt, fcnt, gsum, out);
    }
}

// Round 8
// 99.365 us; speedup vs baseline: 1.0689x; 1.0673x over previous
//
#include <hip/hip_runtime.h>
#include <math.h>

// Chamfer loss, B=4, C=3, Np=Ng=8192, fp32.
// Round 12: FUSED both-axes sweep. R4-R7 established: VALU busy-time pinned
// at ~28.5us = the 2-pass datapath floor (pk_fma = 4cyc/wave64 on SIMD-32);
// schedule, LDS demand, and occupancy all falsified as the duty-gap cause.
// Only remaining lever: compute each d2 pair ONCE, feed both mins.
//   x-side: bit-identical to R4-R7 (s-chain, min3 into mn[r], +p2 at store).
//   y-side: f = s + p2 (2 adds/pair), per-thread min3-tree over r, per-jj
//     v2f -> ybuf[2][8][256] (double-buffered, 32KB); per 8-jj phase one
//     barrier; 32-lane groups fold 256 thread-mins + 5-step shfl_xor,
//     lane0 stores float2 to partialY[b*4+xt][y]. Reduce overlapped with
//     next phase's compute.
// Datapath/jj: 160+6 vs 224 unfused -> 0.74x. Grid (4,64,4)=1024 wgs.
// ws: partialX 8MB + partialY 0.5MB + gsum2 (~8.91MB gate); R0 fallback.

#define B_       4
#define N_       8192
#define THREADS  256
#define RX       8
#define XB       (THREADS * RX)        // 2048 x-points per workgroup
#define XBLKS    (N_ / XB)             // 4
#define YS       64
#define YCHUNK   (N_ / YS)             // 128
#define NJJ      (YCHUNK / 2)          // 64 pair-records
#define RTHREADS 128

#define OFF_PX   0
#define SZ_PX    ((size_t)B_ * YS * N_)            // 2,097,152 floats
#define OFF_PY   SZ_PX
#define SZ_PY    ((size_t)B_ * XBLKS * N_)         // 131,072 floats
#define OFF_GS   (OFF_PY + SZ_PY)
#define WORDS_NEED (OFF_GS + 128)

typedef float v2f __attribute__((ext_vector_type(2)));

__device__ __forceinline__ v2f pk_fma(v2f a, v2f b, v2f c) {
    v2f d;
    asm("v_pk_fma_f32 %0, %1, %2, %3" : "=v"(d) : "v"(a), "v"(b), "v"(c));
    return d;
}

__device__ __forceinline__ float min3f(float a, float b, float c) {
    float d;
    asm("v_min3_f32 %0, %1, %2, %3" : "=v"(d) : "v"(a), "v"(b), "v"(c));
    return d;
}

// ---------------- primary path: fused sweep + reduces ----------------

__global__ __launch_bounds__(THREADS)
void chamfer_fused_sweep(const float* __restrict__ P, const float* __restrict__ G,
                         float* __restrict__ partialX, float* __restrict__ partialY)
{
    __shared__ float4 ytile[2 * NJJ];          // 2 KB
    __shared__ v2f    ybuf[2][8][THREADS];     // 32 KB, double-buffered

    const int t    = threadIdx.x;
    const int xblk = blockIdx.x;   // 0..3
    const int ys   = blockIdx.y;   // 0..63
    const int b    = blockIdx.z;   // 0..3

    const float* Xb = P + (size_t)b * 3 * N_;
    const float* Yb = G + (size_t)b * 3 * N_;

    // Stage y-pair records: 2*jj=(gx0,gx1,gy0,gy1), 2*jj+1=(gz0,gz1,g2_0,g2_1)
    const int ybase = ys * YCHUNK;
    if (t < NJJ) {
        const int n0 = ybase + 2 * t;
        float2 x01 = *(const float2*)&Yb[n0];
        float2 y01 = *(const float2*)&Yb[N_ + n0];
        float2 z01 = *(const float2*)&Yb[2 * N_ + n0];
        float w0 = fmaf(x01.x, x01.x, fmaf(y01.x, y01.x, z01.x * z01.x));
        float w1 = fmaf(x01.y, x01.y, fmaf(y01.y, y01.y, z01.y * z01.y));
        ytile[2 * t]     = make_float4(x01.x, x01.y, y01.x, y01.y);
        ytile[2 * t + 1] = make_float4(z01.x, z01.y, w0, w1);
    }

    // RX x-points per thread; -2*coord duplicated into both halves.
    const int xbase = xblk * XB;
    v2f m2x2[RX], m2y2[RX], m2z2[RX];
    float p2[RX], mn[RX];
#pragma unroll
    for (int r = 0; r < RX; ++r) {
        const int n = xbase + r * THREADS + t;
        float px = Xb[n];
        float py = Xb[N_ + n];
        float pz = Xb[2 * N_ + n];
        p2[r]   = fmaf(px, px, fmaf(py, py, pz * pz));
        float ax = -2.0f * px, ay = -2.0f * py, az = -2.0f * pz;
        m2x2[r] = (v2f){ax, ax};
        m2y2[r] = (v2f){ay, ay};
        m2z2[r] = (v2f){az, az};
        mn[r]   = 3.4e38f;
    }
    __syncthreads();

    // 8 phases x 8 jj. Phase p: compute+write ybuf[p&1]; then (p>0) reduce
    // phase p-1 from ybuf[(p-1)&1]; one barrier per phase.
    for (int p = 0; p < 8; ++p) {
#pragma unroll
        for (int jo = 0; jo < 8; ++jo) {
            const int jj = p * 8 + jo;
            float4 a4 = ytile[2 * jj];       // (gx0,gx1,gy0,gy1)
            float4 b4 = ytile[2 * jj + 1];   // (gz0,gz1,g2_0,g2_1)
            v2f gx2 = (v2f){a4.x, a4.y};
            v2f gy2 = (v2f){a4.z, a4.w};
            v2f gz2 = (v2f){b4.x, b4.y};
            v2f gw2 = (v2f){b4.z, b4.w};
            float fm0, fm1, pfx, pfy;
#pragma unroll
            for (int r = 0; r < RX; ++r) {
                v2f s = pk_fma(m2z2[r], gz2, gw2);
                s = pk_fma(m2y2[r], gy2, s);
                s = pk_fma(m2x2[r], gx2, s);
                mn[r] = min3f(mn[r], s.x, s.y);        // x-side (bit-identical)
                float fx = s.x + p2[r];                 // y-side: full d2
                float fy = s.y + p2[r];
                if (r == 0)      { pfx = fx; pfy = fy; }
                else if (r == 1) { fm0 = fminf(pfx, fx); fm1 = fminf(pfy, fy); }
                else if (r & 1)  { fm0 = min3f(fm0, pfx, fx); fm1 = min3f(fm1, pfy, fy); }
                else             { pfx = fx; pfy = fy; }
            }
            ybuf[p & 1][jo][t] = (v2f){fm0, fm1};
        }
        if (p > 0) {
            const int q = p - 1;
            const int g = t >> 5, lane = t & 31;
            v2f m = ybuf[q & 1][g][lane];
#pragma unroll
            for (int k = 1; k < 8; ++k) {
                v2f v = ybuf[q & 1][g][lane + 32 * k];
                m.x = fminf(m.x, v.x); m.y = fminf(m.y, v.y);
            }
#pragma unroll
            for (int mask = 16; mask >= 1; mask >>= 1) {
                m.x = fminf(m.x, __shfl_xor(m.x, mask));
                m.y = fminf(m.y, __shfl_xor(m.y, mask));
            }
            if (lane == 0) {
                const int y0 = ybase + 2 * (q * 8 + g);
                *(float2*)&partialY[((size_t)b * XBLKS + xblk) * N_ + y0] =
                    make_float2(m.x, m.y);
            }
        }
        __syncthreads();
    }
    {   // reduce final phase (writes completed before last barrier)
        const int q = 7;
        const int g = t >> 5, lane = t & 31;
        v2f m = ybuf[q & 1][g][lane];
#pragma unroll
        for (int k = 1; k < 8; ++k) {
            v2f v = ybuf[q & 1][g][lane + 32 * k];
            m.x = fminf(m.x, v.x); m.y = fminf(m.y, v.y);
        }
#pragma unroll
        for (int mask = 16; mask >= 1; mask >>= 1) {
            m.x = fminf(m.x, __shfl_xor(m.x, mask));
            m.y = fminf(m.y, __shfl_xor(m.y, mask));
        }
        if (lane == 0) {
            const int y0 = ybase + 2 * (q * 8 + g);
            *(float2*)&partialY[((size_t)b * XBLKS + xblk) * N_ + y0] =
                make_float2(m.x, m.y);
        }
    }

    // x epilogue: clamped d2 = mn + p2 (identical to R4-R7 path).
    float* pout = partialX + ((size_t)b * YS + ys) * N_ + xbase;
#pragma unroll
    for (int r = 0; r < RX; ++r)
        pout[r * THREADS + t] = fmaxf(mn[r] + p2[r], 1e-12f);
}

// reduceX: per 4 x-slots: min over YS partials (float4), sqrt, block sum.
__global__ __launch_bounds__(RTHREADS)
void chamfer_reduceX(const float* __restrict__ partialX, float* __restrict__ gsum2)
{
    __shared__ float red[RTHREADS];
    const int g = blockIdx.x * RTHREADS + threadIdx.x;   // [0, 8192)
    const int b = g >> 11;
    const int q = g & 2047;
    const float4* p = (const float4*)(partialX + (size_t)b * YS * N_) + q;
    float4 m = p[0];
#pragma unroll
    for (int ys = 1; ys < YS; ++ys) {
        float4 v = p[(size_t)ys * (N_ / 4)];
        m.x = fminf(m.x, v.x); m.y = fminf(m.y, v.y);
        m.z = fminf(m.z, v.z); m.w = fminf(m.w, v.w);
    }
    red[threadIdx.x] = sqrtf(m.x) + sqrtf(m.y) + sqrtf(m.z) + sqrtf(m.w);
    __syncthreads();
    for (int off = RTHREADS / 2; off > 0; off >>= 1) {
        if (threadIdx.x < off) red[threadIdx.x] += red[threadIdx.x + off];
        __syncthreads();
    }
    if (threadIdx.x == 0) gsum2[blockIdx.x] = red[0];
}

// reduceY: per 4 y-slots: min over XBLKS partials, clamp, sqrt, block sum.
__global__ __launch_bounds__(RTHREADS)
void chamfer_reduceY(const float* __restrict__ partialY, float* __restrict__ gsum2)
{
    __shared__ float red[RTHREADS];
    const int g = blockIdx.x * RTHREADS + threadIdx.x;   // [0, 8192)
    const int b = g >> 11;
    const int q = g & 2047;
    const float4* p = (const float4*)(partialY + (size_t)b * XBLKS * N_) + q;
    float4 m = p[0];
#pragma unroll
    for (int xt = 1; xt < XBLKS; ++xt) {
        float4 v = p[(size_t)xt * (N_ / 4)];
        m.x = fminf(m.x, v.x); m.y = fminf(m.y, v.y);
        m.z = fminf(m.z, v.z); m.w = fminf(m.w, v.w);
    }
    m.x = fmaxf(m.x, 1e-12f); m.y = fmaxf(m.y, 1e-12f);
    m.z = fmaxf(m.z, 1e-12f); m.w = fmaxf(m.w, 1e-12f);
    red[threadIdx.x] = sqrtf(m.x) + sqrtf(m.y) + sqrtf(m.z) + sqrtf(m.w);
    __syncthreads();
    for (int off = RTHREADS / 2; off > 0; off >>= 1) {
        if (threadIdx.x < off) red[threadIdx.x] += red[threadIdx.x + off];
        __syncthreads();
    }
    if (threadIdx.x == 0) gsum2[64 + blockIdx.x] = red[0];
}

// final: deterministic sum of 128 block sums.
__global__ __launch_bounds__(RTHREADS)
void chamfer_final_kernel(const float* __restrict__ gsum2, float* __restrict__ out)
{
    __shared__ float red[RTHREADS];
    red[threadIdx.x] = gsum2[threadIdx.x];
    __syncthreads();
    for (int off = RTHREADS / 2; off > 0; off >>= 1) {
        if (threadIdx.x < off) red[threadIdx.x] += red[threadIdx.x + off];
        __syncthreads();
    }
    if (threadIdx.x == 0) out[0] = red[0] * (1.0f / 65536.0f);   // denom = B*(Ng+Np)
}

// ---------------- fallback path (known-good R0, 257KB ws) ----------------
#define LRX      8
#define LXB      (THREADS * LRX)       // 2048
#define LXBLKS   (N_ / LXB)            // 4
#define LYSPL    32
#define LYCHUNK  (N_ / LYSPL)          // 256
#define LNGROUPS (2 * B_ * LXBLKS)     // 32
#define POISON   0xAAAAAAAAu

__global__ __launch_bounds__(THREADS)
void chamfer_fused_kernel(const float* __restrict__ P, const float* __restrict__ G,
                          unsigned* __restrict__ mins, unsigned* __restrict__ gcnt,
                          unsigned* __restrict__ fcnt, float* __restrict__ gsum,
                          float* __restrict__ out)
{
    __shared__ float4 ytile[2 * (LYCHUNK / 2)];
    __shared__ float red[THREADS];
    __shared__ unsigned s_ticket;

    const int t      = threadIdx.x;
    const int xblk   = blockIdx.x;
    const int ysplit = blockIdx.y;
    const int bz     = blockIdx.z;
    const int pass   = bz >> 2;
    const int b      = bz & 3;
    const int gid    = bz * LXBLKS + xblk;

    const float* Xb = (pass ? G : P) + (size_t)b * 3 * N_;
    const float* Yb = (pass ? P : G) + (size_t)b * 3 * N_;

    const int ybase = ysplit * LYCHUNK;
    if (t < LYCHUNK / 2) {
        const int n0 = ybase + 2 * t;
        float2 x01 = *(const float2*)&Yb[n0];
        float2 y01 = *(const float2*)&Yb[N_ + n0];
        float2 z01 = *(const float2*)&Yb[2 * N_ + n0];
        float w0 = fmaf(x01.x, x01.x, fmaf(y01.x, y01.x, z01.x * z01.x));
        float w1 = fmaf(x01.y, x01.y, fmaf(y01.y, y01.y, z01.y * z01.y));
        ytile[2 * t]     = make_float4(x01.x, x01.y, y01.x, y01.y);
        ytile[2 * t + 1] = make_float4(z01.x, z01.y, w0, w1);
    }

    const int xbase = xblk * LXB;
    v2f m2x2[LRX], m2y2[LRX], m2z2[LRX];
    float p2[LRX], mn[LRX];
#pragma unroll
    for (int r = 0; r < LRX; ++r) {
        const int n = xbase + r * THREADS + t;
        float px = Xb[n];
        float py = Xb[N_ + n];
        float pz = Xb[2 * N_ + n];
        p2[r]   = fmaf(px, px, fmaf(py, py, pz * pz));
        float ax = -2.0f * px, ay = -2.0f * py, az = -2.0f * pz;
        m2x2[r] = (v2f){ax, ax};
        m2y2[r] = (v2f){ay, ay};
        m2z2[r] = (v2f){az, az};
        mn[r]   = 3.4e38f;
    }
    __syncthreads();

#pragma unroll 2
    for (int jj = 0; jj < LYCHUNK / 2; ++jj) {
        float4 a4 = ytile[2 * jj];
        float4 b4 = ytile[2 * jj + 1];
        v2f gx2 = (v2f){a4.x, a4.y};
        v2f gy2 = (v2f){a4.z, a4.w};
        v2f gz2 = (v2f){b4.x, b4.y};
        v2f gw2 = (v2f){b4.z, b4.w};
#pragma unroll
        for (int r = 0; r < LRX; ++r) {
            v2f s = pk_fma(m2z2[r], gz2, gw2);
            s = pk_fma(m2y2[r], gy2, s);
            s = pk_fma(m2x2[r], gx2, s);
            mn[r] = fminf(fminf(mn[r], s.x), s.y);
        }
    }

    unsigned* mybase = mins + (size_t)(pass * B_ + b) * N_ + xbase;
#pragma unroll
    for (int r = 0; r < LRX; ++r) {
        float v = fmaxf(mn[r] + p2[r], 1e-12f);
        atomicMin(&mybase[r * THREADS + t], __float_as_uint(v));
    }

    __syncthreads();
    if (t == 0) {
        __threadfence();
        s_ticket = atomicAdd(&gcnt[gid], 1u);
    }
    __syncthreads();
    if (s_ticket != POISON + (unsigned)(LYSPL - 1)) return;

    __threadfence();
    const uint4* vmin = (const uint4*)(mins + (size_t)(pass * B_ + b) * N_ + xbase);
    uint4 q0 = vmin[t];
    uint4 q1 = vmin[THREADS + t];
    float a = sqrtf(__uint_as_float(q0.x)) + sqrtf(__uint_as_float(q0.y))
            + sqrtf(__uint_as_float(q0.z)) + sqrtf(__uint_as_float(q0.w))
            + sqrtf(__uint_as_float(q1.x)) + sqrtf(__uint_as_float(q1.y))
            + sqrtf(__uint_as_float(q1.z)) + sqrtf(__uint_as_float(q1.w));
    red[t] = a;
    __syncthreads();
    for (int off = 128; off > 0; off >>= 1) {
        if (t < off) red[t] += red[t + off];
        __syncthreads();
    }
    if (t == 0) {
        gsum[gid] = red[0];
        __threadfence();
        s_ticket = atomicAdd(fcnt, 1u);
    }
    __syncthreads();
    if (s_ticket != POISON + (unsigned)(LNGROUPS - 1)) return;

    __threadfence();
    red[t] = (t < LNGROUPS) ? gsum[t] : 0.0f;
    __syncthreads();
    for (int off = 128; off > 0; off >>= 1) {
        if (t < off) red[t] += red[t + off];
        __syncthreads();
    }
    if (t == 0) out[0] = red[0] * (1.0f / 65536.0f);
}

extern "C" void kernel_launch(void* const* d_in, const int* in_sizes, int n_in,
                              void* d_out, int out_size, void* d_ws, size_t ws_size,
                              hipStream_t stream)
{
    const float* P = (const float*)d_in[0];   // predict_pc [4,3,8192]
    const float* G = (const float*)d_in[1];   // gt_pc      [4,3,8192]
    float* out = (float*)d_out;               // scalar

    if (ws_size >= (size_t)WORDS_NEED * 4) {
        float* wsf      = (float*)d_ws;
        float* partialX = wsf + OFF_PX;
        float* partialY = wsf + OFF_PY;
        float* gsum2    = wsf + OFF_GS;
        chamfer_fused_sweep<<<dim3(XBLKS, YS, B_), THREADS, 0, stream>>>(P, G, partialX, partialY);
        chamfer_reduceX<<<dim3(64), RTHREADS, 0, stream>>>(partialX, gsum2);
        chamfer_reduceY<<<dim3(64), RTHREADS, 0, stream>>>(partialY, gsum2);
        chamfer_final_kernel<<<dim3(1), RTHREADS, 0, stream>>>(gsum2, out);
    } else {
        unsigned* w    = (unsigned*)d_ws;
        unsigned* mins = w;                   // 65536 words
        unsigned* gcnt = w + 65536;           // 32 words
        unsigned* fcnt = w + 65600;           // 1 word
        float*    gsum = (float*)(w + 65664); // 32 words
        dim3 grid(LXBLKS, LYSPL, 2 * B_);
        chamfer_fused_kernel<<<grid, THREADS, 0, stream>>>(P, G, mins, gcnt, fcnt, gsum, out);
    }
}